// Round 15
// baseline (331.224 us; speedup 1.0000x reference)
//
#include <hip/hip_runtime.h>

// MHA forward: B=2, S=2048, D=1024, H=16, hd=64. fp32 in/out, bf16 MFMA inside.
// ws regions (ushort elems, 4194304 each):
//   [0]=q [1]=k [2]=vt (written directly by gemm_qkv epilogue)
//   [3]=WqkvT(->ctx after attn starts) [4]=xbf(->Opart/lpart/cnt during attn)
//   [5 if ws allows]=woT (2 MB) -> fused prep path
// K is prescaled by 0.125*log2(e) so attention softmax runs in exp2 domain.
// attn split-K: no-max exp2 softmax => partials combine by pure summation.
// Chunk-0 partials live (unnormalized) in ctx; chunks>=1 in Opart. The LAST chunk
// to finish (device-scope atomic counter) performs the normalize-combine in-kernel.

typedef __attribute__((ext_vector_type(8))) __bf16 bf16x8;
typedef __attribute__((ext_vector_type(4))) float f32x4;
typedef __attribute__((ext_vector_type(4))) short short4v;

__device__ __forceinline__ unsigned short f2bf(float f) {
    union { float f; unsigned u; } v; v.f = f;
    unsigned r = v.u + 0x7fffu + ((v.u >> 16) & 1u);  // RNE
    return (unsigned short)(r >> 16);
}

__device__ __forceinline__ float bf2f(unsigned short u) {
    return __builtin_bit_cast(float, (unsigned)u << 16);
}

__device__ __forceinline__ unsigned pack_bf16x2_trunc(float a, float b) {
#if defined(__HIP_DEVICE_COMPILE__)
    return __builtin_amdgcn_perm(__builtin_bit_cast(unsigned, a),
                                 __builtin_bit_cast(unsigned, b), 0x03020706u);
#else
    return 0u;
#endif
}

__device__ __forceinline__ float fast_exp2(float x) {
#if defined(__HIP_DEVICE_COMPILE__)
    return __builtin_amdgcn_exp2f(x);
#else
    return x;
#endif
}

__device__ __forceinline__ void async_copy16(const unsigned short* g, unsigned short* l) {
    __builtin_amdgcn_global_load_lds(
        (const __attribute__((address_space(1))) unsigned int*)g,
        (__attribute__((address_space(3))) unsigned int*)l, 16, 0, 0);
}

__device__ __forceinline__ f32x4 mfma16x16x16(short4v a, short4v b, f32x4 c) {
#if defined(__HIP_DEVICE_COMPILE__)
    return __builtin_amdgcn_mfma_f32_16x16x16bf16_1k(a, b, c, 0, 0, 0);
#else
    return c;
#endif
}

// ---------------- prep bodies ----------------
__device__ __forceinline__ void convert_body(
    const float* __restrict__ in, unsigned short* __restrict__ out, int blk)
{
    size_t i = ((size_t)blk * 256 + threadIdx.x) * 8;
    float4 v0 = *(const float4*)(in + i);
    float4 v1 = *(const float4*)(in + i + 4);
    ushort4 a, b;
    a.x = f2bf(v0.x); a.y = f2bf(v0.y); a.z = f2bf(v0.z); a.w = f2bf(v0.w);
    b.x = f2bf(v1.x); b.y = f2bf(v1.y); b.z = f2bf(v1.z); b.w = f2bf(v1.w);
    *(ushort4*)(out + i) = a;
    *(ushort4*)(out + i + 4) = b;
}

__device__ __forceinline__ void transpose_body(
    const float* __restrict__ in, unsigned short* __restrict__ out,
    int K, int N, int bx, int by, float T[64][65])
{
    const int tid = threadIdx.x;
    const int n0 = bx * 64, k0 = by * 64;
#pragma unroll
    for (int i = 0; i < 4; i++) {
        int idx = tid + i * 256;
        int r = idx >> 4, c4 = (idx & 15) * 4;
        float4 v = *(const float4*)(in + (size_t)(k0 + r) * N + n0 + c4);
        T[r][c4 + 0] = v.x; T[r][c4 + 1] = v.y; T[r][c4 + 2] = v.z; T[r][c4 + 3] = v.w;
    }
    __syncthreads();
#pragma unroll
    for (int i = 0; i < 4; i++) {
        int idx = tid + i * 256;
        int n = idx >> 4, k4 = (idx & 15) * 4;
        ushort4 o;
        o.x = f2bf(T[k4 + 0][n]); o.y = f2bf(T[k4 + 1][n]);
        o.z = f2bf(T[k4 + 2][n]); o.w = f2bf(T[k4 + 3][n]);
        *(ushort4*)(out + (size_t)(n0 + n) * K + k0 + k4) = o;
    }
}

__global__ __launch_bounds__(256) void prep(
    const float* __restrict__ x, const float* __restrict__ Wqkv, const float* __restrict__ Wo,
    unsigned short* __restrict__ xbf, unsigned short* __restrict__ wqkvT,
    unsigned short* __restrict__ woT)
{
    __shared__ float T[64][65];
    const int i = blockIdx.x;
    if (i < 2048) {
        convert_body(x, xbf, i);
    } else if (i < 2048 + 768) {
        int j = i - 2048;
        transpose_body(Wqkv, wqkvT, 1024, 3072, j % 48, j / 48, T);
    } else {
        int j = i - 2816;
        transpose_body(Wo, woT, 1024, 1024, j % 16, j / 16, T);
    }
}

__global__ __launch_bounds__(256) void convert_f32_bf16(
    const float* __restrict__ in, unsigned short* __restrict__ out)
{
    convert_body(in, out, blockIdx.x);
}

__global__ __launch_bounds__(256) void transpose_f32_bf16(
    const float* __restrict__ in, unsigned short* __restrict__ out, int K, int N)
{
    __shared__ float T[64][65];
    transpose_body(in, out, K, N, blockIdx.x, blockIdx.y, T);
}

// ---------------- GEMM1: qkv = Xbf @ WqkvT (+bqkv). Coalesced epilogue writes
// q/k row-major AND vt=[bh][d][s] directly (per-block v-columns are one aligned
// 64-col half with uniform h; transposed via the Tv LDS tile). ----------------
__global__ __launch_bounds__(256) void gemm_qkv_bf(
    const unsigned short* __restrict__ Xbf,  // [4096][1024] bf16
    const unsigned short* __restrict__ WT,   // [3072][1024] bf16
    const float* __restrict__ bias,
    unsigned short* __restrict__ qws, unsigned short* __restrict__ kws,
    unsigned short* __restrict__ vt)         // [32][64][2048]
{
    const int K = 1024;
    __shared__ __align__(16) unsigned short smem[128 * 136];  // staging union / C-tile
    __shared__ __align__(16) unsigned short Tv[64 * 146];     // v-transpose tile
    unsigned short* As = smem;
    unsigned short* Bs = smem + 8192;
    const int tid = threadIdx.x;
    const int m0 = blockIdx.y * 128, n0 = blockIdx.x * 128;
    const int phase = blockIdx.x % 3;   // 0: q|k, 1: v|q, 2: k|v
    const int wave = tid >> 6, lane = tid & 63;
    const int wm = (wave >> 1) * 64, wn = (wave & 1) * 64;
    const int quad = lane >> 4, l16 = lane & 15;
    const int lrow = lane >> 3, lgrp = lane & 7;
    const int sg = lgrp ^ lrow;

    f32x4 acc[4][4];
    const f32x4 Z4 = {0.f, 0.f, 0.f, 0.f};
#pragma unroll
    for (int i = 0; i < 4; i++)
#pragma unroll
        for (int j = 0; j < 4; j++) acc[i][j] = Z4;

    for (int k0 = 0; k0 < K; k0 += 64) {
        __syncthreads();
#pragma unroll
        for (int c = 0; c < 4; c++) {
            int nb = (wave * 4 + c) * 8;
            async_copy16(Xbf + (size_t)(m0 + nb + lrow) * K + k0 + sg * 8, &As[nb * 64]);
            async_copy16(WT  + (size_t)(n0 + nb + lrow) * K + k0 + sg * 8, &Bs[nb * 64]);
        }
        __syncthreads();
#pragma unroll
        for (int kk = 0; kk < 2; kk++) {
            int pg = ((kk * 4 + quad) ^ (l16 & 7)) * 8;
            bf16x8 af[4], bfr[4];
#pragma unroll
            for (int mi = 0; mi < 4; mi++) af[mi] = *(const bf16x8*)&As[(wm + mi * 16 + l16) * 64 + pg];
#pragma unroll
            for (int ni = 0; ni < 4; ni++) bfr[ni] = *(const bf16x8*)&Bs[(wn + ni * 16 + l16) * 64 + pg];
#pragma unroll
            for (int mi = 0; mi < 4; mi++)
#pragma unroll
                for (int ni = 0; ni < 4; ni++)
                    acc[mi][ni] = __builtin_amdgcn_mfma_f32_16x16x32_bf16(af[mi], bfr[ni], acc[mi][ni], 0, 0, 0);
        }
    }
    // ---- epilogue pass 1: bias (+k prescale) -> bf16 -> C-tile / Tv ----
    __syncthreads();
#pragma unroll
    for (int ni = 0; ni < 4; ni++) {
        int colL = wn + ni * 16 + l16;
        int col = n0 + colL;
        int rem = col % 192, t = rem >> 6;
        float bv = bias[col];
        if (t == 2) {  // wave-uniform per ni
#pragma unroll
            for (int mi = 0; mi < 4; mi++)
#pragma unroll
                for (int r = 0; r < 4; r++) {
                    int row = wm + mi * 16 + quad * 4 + r;
                    Tv[(colL & 63) * 146 + row] = f2bf(acc[mi][ni][r] + bv);
                }
        } else {
            float scl = (t == 1) ? 0.18033688f : 1.0f;  // 0.125*log2(e) folded into K
#pragma unroll
            for (int mi = 0; mi < 4; mi++)
#pragma unroll
                for (int r = 0; r < 4; r++) {
                    int row = wm + mi * 16 + quad * 4 + r;
                    smem[row * 136 + colL] = f2bf((acc[mi][ni][r] + bv) * scl);
                }
        }
    }
    __syncthreads();
    // ---- epilogue pass 2: coalesced 16B/lane stores ----
    if (phase == 0) {
#pragma unroll
        for (int i = 0; i < 8; i++) {
            int idx = tid + i * 256;
            int row = idx >> 4, g = idx & 15;
            int colL = g * 8;
            uint4 w = *(const uint4*)&smem[row * 136 + colL];
            int col = n0 + colL;
            int h = col / 192, rem = col % 192, t = rem >> 6, d = rem & 63;
            int grow = m0 + row;
            int b = grow >> 11, s = grow & 2047;
            unsigned short* dst = (t == 0) ? qws : kws;  // phase 0: never v
            *(uint4*)(dst + ((size_t)(b * 16 + h) * 2048 + s) * 64 + d) = w;
        }
    } else {
        const int qkb = (phase == 1) ? 64 : 0;   // local base of the q/k half
#pragma unroll
        for (int i = 0; i < 4; i++) {
            int idx = tid + i * 256;             // 128 rows x 8 groups
            int row = idx >> 3, g = idx & 7;
            int colL = qkb + g * 8;
            uint4 w = *(const uint4*)&smem[row * 136 + colL];
            int col = n0 + colL;
            int h = col / 192, rem = col % 192, t = rem >> 6, d = rem & 63;
            int grow = m0 + row;
            int b = grow >> 11, s = grow & 2047;
            unsigned short* dst = (t == 0) ? qws : kws;
            *(uint4*)(dst + ((size_t)(b * 16 + h) * 2048 + s) * 64 + d) = w;
        }
        const int vbase = (phase == 1) ? 0 : 64;
        const int hv = (n0 + vbase) / 192;       // uniform per block
        const int bb = m0 >> 11, s0 = m0 & 2047;
        unsigned short* vtb = vt + ((size_t)(bb * 16 + hv) * 64) * 2048 + s0;
#pragma unroll
        for (int i = 0; i < 4; i++) {
            int idx = tid + i * 256;             // 64 d x 16 row-groups
            int d = idx >> 4, rg = idx & 15;
            uint4 w = *(const uint4*)&Tv[d * 146 + rg * 8];
            *(uint4*)(vtb + (size_t)d * 2048 + rg * 8) = w;
        }
    }
}

// ---------------- Flash attention (causal), S-transposed, fine split-K,
// in-kernel atomic-counter fixup (no separate combine dispatch) ----------------
// Tiles 0..11 unsplit; 12..23 2-way; 24..31 3-way (all chunks <= 12 kv-iters).
#define J(t, s, e, c) ((unsigned)(t) | ((unsigned)(s) << 8) | ((unsigned)(e) << 16) | ((unsigned)(c) << 24))
__device__ __constant__ unsigned ATTN_JOBS[60] = {
    J(22,0,12,0), J(23,0,12,0), J(23,12,24,1), J(11,0,12,0),
    J(20,0,11,0), J(21,0,11,0), J(21,11,22,1), J(22,12,23,1),
    J(30,0,11,0), J(31,0,11,0), J(31,11,22,1), J(10,0,11,0),
    J(18,0,10,0), J(19,0,10,0), J(19,10,20,1), J(20,11,21,1),
    J(27,0,10,0), J(28,0,10,0), J(28,10,20,1), J(29,0,10,0),
    J(29,10,20,1), J(29,20,30,2), J(30,11,21,1), J(30,21,31,2),
    J(31,22,32,2), J(9,0,10,0),
    J(16,0,9,0), J(17,0,9,0), J(17,9,18,1), J(18,10,19,1),
    J(24,0,9,0), J(25,0,9,0), J(25,9,18,1), J(26,0,9,0),
    J(26,9,18,1), J(26,18,27,2), J(27,10,19,1), J(27,19,28,2),
    J(28,20,29,2), J(8,0,9,0),
    J(14,0,8,0), J(15,0,8,0), J(15,8,16,1), J(16,9,17,1),
    J(24,9,17,1), J(24,17,25,2), J(25,18,26,2), J(7,0,8,0),
    J(12,0,7,0), J(13,0,7,0), J(13,7,14,1), J(14,8,15,1), J(6,0,7,0),
    J(12,7,13,1), J(5,0,6,0), J(4,0,5,0), J(3,0,4,0), J(2,0,3,0),
    J(1,0,2,0), J(0,0,1,0),
};
#undef J

__global__ __launch_bounds__(128) void attn(
    const unsigned short* __restrict__ qws, const unsigned short* __restrict__ kws,
    const unsigned short* __restrict__ vtws, unsigned short* __restrict__ ctx,
    unsigned short* __restrict__ Opart, float* __restrict__ lpart, int* __restrict__ cnt)
{
    __shared__ __align__(16) unsigned short Qs[64 * 64];
    __shared__ __align__(16) unsigned short Ks[64 * 64];
    __shared__ __align__(16) unsigned short Vt[64][72];
    __shared__ int s_old;

    const int tid = threadIdx.x;
    const int wave = tid >> 6, lane = tid & 63, quad = lane >> 4, l16 = lane & 15;
    const int lrow = lane >> 3, lgrp = lane & 7;
    const int sg = lgrp ^ lrow;

    const unsigned job = ATTN_JOBS[blockIdx.x >> 5];
    const int bh = blockIdx.x & 31;
    const int tile = job & 0xff;
    const int js = (job >> 8) & 0xff, je = (job >> 16) & 0xff;
    const int chunk = (job >> 24) & 0xff;
    const int q0 = tile * 64;
    const bool split = tile >= 12;

    const unsigned short* Q  = qws + (size_t)bh * 2048 * 64;
    const unsigned short* Kp = kws + (size_t)bh * 2048 * 64;
    const unsigned short* Vp = vtws + (size_t)bh * 64 * 2048;

#pragma unroll
    for (int c = 0; c < 4; c++) {
        int rb = (wave * 4 + c) * 8;
        async_copy16(Q + (size_t)(q0 + rb + lrow) * 64 + sg * 8, &Qs[rb * 64]);
    }

    const int wq = wave * 32;
    f32x4 o[4][2];
    const f32x4 Z4 = {0.f, 0.f, 0.f, 0.f};
#pragma unroll
    for (int dt = 0; dt < 4; dt++)
#pragma unroll
        for (int qt = 0; qt < 2; qt++) o[dt][qt] = Z4;
    float lsum[2] = {0.f, 0.f};

    for (int j = js; j < je; j++) {
        const int kb0 = j * 64;
        __syncthreads();
#pragma unroll
        for (int c = 0; c < 4; c++) {
            int rb = (wave * 4 + c) * 8;
            async_copy16(Kp + (size_t)(kb0 + rb + lrow) * 64 + sg * 8, &Ks[rb * 64]);
        }
#pragma unroll
        for (int ii = 0; ii < 4; ii++) {
            int id2 = tid + ii * 128;
            int row = id2 >> 3, c = (id2 & 7) * 8;
            *(uint4*)&Vt[row][c] = *(const uint4*)(Vp + (size_t)row * 2048 + kb0 + c);
        }
        __syncthreads();

        if (kb0 <= q0 + wq + 31) {
            f32x4 sc[4][2];
#pragma unroll
            for (int kt = 0; kt < 4; kt++)
#pragma unroll
                for (int qt = 0; qt < 2; qt++) sc[kt][qt] = Z4;
#pragma unroll
            for (int kk = 0; kk < 2; kk++) {
                int pg = ((kk * 4 + quad) ^ (l16 & 7)) * 8;
                bf16x8 ak[4], bq[2];
#pragma unroll
                for (int kt = 0; kt < 4; kt++) ak[kt] = *(const bf16x8*)&Ks[(kt * 16 + l16) * 64 + pg];
#pragma unroll
                for (int qt = 0; qt < 2; qt++) bq[qt] = *(const bf16x8*)&Qs[(wq + qt * 16 + l16) * 64 + pg];
#pragma unroll
                for (int kt = 0; kt < 4; kt++)
#pragma unroll
                    for (int qt = 0; qt < 2; qt++)
                        sc[kt][qt] = __builtin_amdgcn_mfma_f32_16x16x32_bf16(ak[kt], bq[qt], sc[kt][qt], 0, 0, 0);
            }
            short4v pb[4][2];
            if (kb0 + 63 <= q0 + wq) {
#pragma unroll
                for (int qt = 0; qt < 2; qt++)
#pragma unroll
                    for (int kt = 0; kt < 4; kt++) {
                        float p0 = fast_exp2(sc[kt][qt][0]);
                        float p1 = fast_exp2(sc[kt][qt][1]);
                        float p2 = fast_exp2(sc[kt][qt][2]);
                        float p3 = fast_exp2(sc[kt][qt][3]);
                        lsum[qt] += (p0 + p1) + (p2 + p3);
                        uint2 uu;
                        uu.x = pack_bf16x2_trunc(p0, p1);
                        uu.y = pack_bf16x2_trunc(p2, p3);
                        pb[kt][qt] = __builtin_bit_cast(short4v, uu);
                    }
            } else {
#pragma unroll
                for (int qt = 0; qt < 2; qt++) {
                    int qg = q0 + wq + qt * 16 + l16;
#pragma unroll
                    for (int kt = 0; kt < 4; kt++) {
                        float p[4];
#pragma unroll
                        for (int r = 0; r < 4; r++) {
                            int key = kb0 + kt * 16 + quad * 4 + r;
                            float t = fast_exp2(sc[kt][qt][r]);
                            p[r] = (key <= qg) ? t : 0.f;
                        }
                        lsum[qt] += (p[0] + p[1]) + (p[2] + p[3]);
                        uint2 uu;
                        uu.x = pack_bf16x2_trunc(p[0], p[1]);
                        uu.y = pack_bf16x2_trunc(p[2], p[3]);
                        pb[kt][qt] = __builtin_bit_cast(short4v, uu);
                    }
                }
            }
#pragma unroll
            for (int kt = 0; kt < 4; kt++) {
#pragma unroll
                for (int dt = 0; dt < 4; dt++) {
                    short4v av = *(const short4v*)&Vt[dt * 16 + l16][kt * 16 + quad * 4];
#pragma unroll
                    for (int qt = 0; qt < 2; qt++)
                        o[dt][qt] = mfma16x16x16(av, pb[kt][qt], o[dt][qt]);
                }
            }
        }
    }
#pragma unroll
    for (int qt = 0; qt < 2; qt++) {
        lsum[qt] += __shfl_xor(lsum[qt], 16);
        lsum[qt] += __shfl_xor(lsum[qt], 32);
    }
    const int b = bh >> 4, h = bh & 15;
    if (!split) {
#pragma unroll
        for (int qt = 0; qt < 2; qt++) {
            int qg = q0 + wq + qt * 16 + l16;
            float inv = 1.0f / lsum[qt];
#pragma unroll
            for (int dt = 0; dt < 4; dt++) {
                ushort4 ov;
                ov.x = f2bf(o[dt][qt][0] * inv);
                ov.y = f2bf(o[dt][qt][1] * inv);
                ov.z = f2bf(o[dt][qt][2] * inv);
                ov.w = f2bf(o[dt][qt][3] * inv);
                *(ushort4*)(ctx + (size_t)(b * 2048 + qg) * 1024 + h * 64 + dt * 16 + quad * 4) = ov;
            }
        }
        return;
    }
    // ---- split: store partial + lsum, then last-chunk fixup ----
    const int nch = (tile < 24) ? 2 : 3;
    const int ls0 = (tile < 24) ? (tile - 12) * 2 : 24 + (tile - 24) * 3;
    const int os0 = (tile < 24) ? (tile - 12) : 12 + (tile - 24) * 2;
    const int ls = ls0 + chunk;
    float* lp0 = lpart + ((size_t)bh * 48 + ls) * 64;
#pragma unroll
    for (int qt = 0; qt < 2; qt++) {
        int rl = wq + qt * 16 + l16;
        if (quad == 0) lp0[rl] = lsum[qt];
    }
    if (chunk == 0) {
#pragma unroll
        for (int qt = 0; qt < 2; qt++) {
            int qg = q0 + wq + qt * 16 + l16;
#pragma unroll
            for (int dt = 0; dt < 4; dt++) {
                ushort4 ov;
                ov.x = f2bf(o[dt][qt][0]);
                ov.y = f2bf(o[dt][qt][1]);
                ov.z = f2bf(o[dt][qt][2]);
                ov.w = f2bf(o[dt][qt][3]);
                *(ushort4*)(ctx + (size_t)(b * 2048 + qg) * 1024 + h * 64 + dt * 16 + quad * 4) = ov;
            }
        }
    } else {
        unsigned short* ob = Opart + ((size_t)bh * 28 + os0 + (chunk - 1)) * 4096;
#pragma unroll
        for (int qt = 0; qt < 2; qt++) {
            int rl = wq + qt * 16 + l16;
#pragma unroll
            for (int dt = 0; dt < 4; dt++) {
                ushort4 ov;
                ov.x = f2bf(o[dt][qt][0]);
                ov.y = f2bf(o[dt][qt][1]);
                ov.z = f2bf(o[dt][qt][2]);
                ov.w = f2bf(o[dt][qt][3]);
                *(ushort4*)(ob + (size_t)rl * 64 + dt * 16 + quad * 4) = ov;
            }
        }
    }
    __threadfence();
    __syncthreads();
    if (tid == 0) s_old = atomicAdd(&cnt[bh * 20 + (tile - 12)], 1);
    __syncthreads();
    if (s_old == nch - 1) {
        __threadfence();
        const float* lp = lpart + ((size_t)bh * 48 + ls0) * 64;
        const unsigned short* pb1 = Opart + ((size_t)bh * 28 + os0) * 4096;
        unsigned short* cbase = ctx + ((size_t)(b * 2048 + tile * 64)) * 1024 + h * 64;
#pragma unroll
        for (int it = 0; it < 4; it++) {
            int idx = tid + it * 128;
            int row = idx >> 3, g = (idx & 7) * 8;
            float ls2 = lp[row] + lp[64 + row];
            if (nch == 3) ls2 += lp[128 + row];
            float inv = 1.0f / ls2;
            unsigned short* dst = cbase + (size_t)row * 1024 + g;
            ushort a0[8], a1[8], a2[8], ov[8];
            *(uint4*)a0 = *(const uint4*)dst;
            *(uint4*)a1 = *(const uint4*)(pb1 + (size_t)row * 64 + g);
            if (nch == 3) *(uint4*)a2 = *(const uint4*)(pb1 + 4096 + (size_t)row * 64 + g);
#pragma unroll
            for (int e = 0; e < 8; e++) {
                float f = bf2f(a0[e]) + bf2f(a1[e]);
                if (nch == 3) f += bf2f(a2[e]);
                ov[e] = f2bf(f * inv);
            }
            *(uint4*)dst = *(const uint4*)ov;
        }
    }
}

// ---------------- GEMM2: out = ctx @ Wo + bo (fp32 out), 64x128 tiles (512 blocks) ----------------
__global__ __launch_bounds__(256) void gemm_out(
    const unsigned short* __restrict__ Ctx, const unsigned short* __restrict__ WT,
    const float* __restrict__ bias, float* __restrict__ Out)
{
    const int K = 1024, N = 1024;
    __shared__ __align__(16) unsigned short As[64 * 64];
    __shared__ __align__(16) unsigned short Bs[128 * 64];
    const int tid = threadIdx.x;
    const int m0 = blockIdx.y * 64, n0 = blockIdx.x * 128;
    const int wave = tid >> 6, lane = tid & 63;
    const int wm = (wave >> 1) * 32, wn = (wave & 1) * 64;
    const int quad = lane >> 4, l16 = lane & 15;
    const int lrow = lane >> 3, lgrp = lane & 7;
    const int sg = lgrp ^ lrow;

    f32x4 acc[2][4];
    const f32x4 Z4 = {0.f, 0.f, 0.f, 0.f};
#pragma unroll
    for (int i = 0; i < 2; i++)
#pragma unroll
        for (int j = 0; j < 4; j++) acc[i][j] = Z4;

    for (int k0 = 0; k0 < K; k0 += 64) {
        __syncthreads();
#pragma unroll
        for (int c = 0; c < 2; c++) {
            int nb = (wave * 2 + c) * 8;
            async_copy16(Ctx + (size_t)(m0 + nb + lrow) * K + k0 + sg * 8, &As[nb * 64]);
        }
#pragma unroll
        for (int c = 0; c < 4; c++) {
            int nb = (wave * 4 + c) * 8;
            async_copy16(WT + (size_t)(n0 + nb + lrow) * K + k0 + sg * 8, &Bs[nb * 64]);
        }
        __syncthreads();
#pragma unroll
        for (int kk = 0; kk < 2; kk++) {
            int pg = ((kk * 4 + quad) ^ (l16 & 7)) * 8;
            bf16x8 af[2], bfr[4];
#pragma unroll
            for (int mi = 0; mi < 2; mi++) af[mi] = *(const bf16x8*)&As[(wm + mi * 16 + l16) * 64 + pg];
#pragma unroll
            for (int ni = 0; ni < 4; ni++) bfr[ni] = *(const bf16x8*)&Bs[(wn + ni * 16 + l16) * 64 + pg];
#pragma unroll
            for (int mi = 0; mi < 2; mi++)
#pragma unroll
                for (int ni = 0; ni < 4; ni++)
                    acc[mi][ni] = __builtin_amdgcn_mfma_f32_16x16x32_bf16(af[mi], bfr[ni], acc[mi][ni], 0, 0, 0);
        }
    }
#pragma unroll
    for (int mi = 0; mi < 2; mi++)
#pragma unroll
        for (int ni = 0; ni < 4; ni++) {
            int col = n0 + wn + ni * 16 + l16;
            float bv = bias[col];
#pragma unroll
            for (int r = 0; r < 4; r++) {
                int row = m0 + wm + mi * 16 + quad * 4 + r;
                Out[(size_t)row * N + col] = acc[mi][ni][r] + bv;
            }
        }
}

extern "C" void kernel_launch(void* const* d_in, const int* in_sizes, int n_in,
                              void* d_out, int out_size, void* d_ws, size_t ws_size,
                              hipStream_t stream) {
    const float* x    = (const float*)d_in[0];
    const float* Wqkv = (const float*)d_in[1];
    const float* bqkv = (const float*)d_in[2];
    const float* Wo   = (const float*)d_in[3];
    const float* bo   = (const float*)d_in[4];
    float* out = (float*)d_out;

    const size_t R = 4194304;  // ushorts per region (8 MB)
    unsigned short* q    = (unsigned short*)d_ws;
    unsigned short* k    = q + R;
    unsigned short* vt   = k + R;     // region 2: written directly by gemm_qkv
    unsigned short* ctx  = vt + R;    // region 3 (wqkvT before attn)
    unsigned short* xbf  = ctx + R;   // region 4: xbf during gemm; Opart/lpart/cnt during attn
    unsigned short* wqkvT = ctx;
    // split-K scratch in region 4 (xbf dead after gemm_qkv_bf):
    unsigned short* Opart = xbf;                           // 896 slots * 4096 ushorts
    float* lpart = (float*)(xbf + (size_t)896 * 4096);     // 1536 slots * 64 fp32
    int* cnt = (int*)(xbf + (size_t)896 * 4096 + 196608);  // 640 ints

    if (ws_size >= 2 * (5 * R + 1048576)) {
        unsigned short* woT5 = q + 5 * R;
        prep<<<dim3(3072), 256, 0, stream>>>(x, Wqkv, Wo, xbf, wqkvT, woT5);
        gemm_qkv_bf<<<dim3(24, 32), 256, 0, stream>>>(xbf, wqkvT, bqkv, q, k, vt);
        hipMemsetAsync(cnt, 0, 640 * sizeof(int), stream);
        attn<<<dim3(1920), 128, 0, stream>>>(q, k, vt, ctx, Opart, lpart, cnt);
        gemm_out<<<dim3(8, 64), 256, 0, stream>>>(ctx, woT5, bo, out);
    } else {
        unsigned short* woT = q;  // alias: q dead after attn
        convert_f32_bf16<<<dim3(2048), 256, 0, stream>>>(x, xbf);
        transpose_f32_bf16<<<dim3(48, 16), 256, 0, stream>>>(Wqkv, wqkvT, 1024, 3072);
        gemm_qkv_bf<<<dim3(24, 32), 256, 0, stream>>>(xbf, wqkvT, bqkv, q, k, vt);
        hipMemsetAsync(cnt, 0, 640 * sizeof(int), stream);
        attn<<<dim3(1920), 128, 0, stream>>>(q, k, vt, ctx, Opart, lpart, cnt);
        transpose_f32_bf16<<<dim3(16, 16), 256, 0, stream>>>(Wo, woT, 1024, 1024);
        gemm_out<<<dim3(8, 64), 256, 0, stream>>>(ctx, woT, bo, out);
    }
}

// Round 16
// 183.924 us; speedup vs baseline: 1.8009x; 1.8009x over previous
//
#include <hip/hip_runtime.h>

// MHA forward: B=2, S=2048, D=1024, H=16, hd=64. fp32 in/out, bf16 MFMA inside.
// ws regions (ushort elems, 4194304 each):
//   [0]=q [1]=k [2]=vt (written directly by gemm_qkv epilogue)
//   [3]=WqkvT(->ctx after attn starts) [4]=xbf(->Opart/lpart during attn)
//   [5 if ws allows]=woT (2 MB) -> fused prep path
// K is prescaled by 0.125*log2(e) so attention softmax runs in exp2 domain.
// attn split-K: no-max exp2 softmax => partials combine by pure summation.
// Chunk-0 partials live (unnormalized) in ctx; chunks>=1 in Opart; a separate
// small combine dispatch normalizes (NO device-scope fences on the hot path —
// r15 showed __threadfence() per block costs ~L2-writeback each, 7x regression).

typedef __attribute__((ext_vector_type(8))) __bf16 bf16x8;
typedef __attribute__((ext_vector_type(4))) float f32x4;
typedef __attribute__((ext_vector_type(4))) short short4v;

__device__ __forceinline__ unsigned short f2bf(float f) {
    union { float f; unsigned u; } v; v.f = f;
    unsigned r = v.u + 0x7fffu + ((v.u >> 16) & 1u);  // RNE
    return (unsigned short)(r >> 16);
}

__device__ __forceinline__ float bf2f(unsigned short u) {
    return __builtin_bit_cast(float, (unsigned)u << 16);
}

__device__ __forceinline__ unsigned pack_bf16x2_trunc(float a, float b) {
#if defined(__HIP_DEVICE_COMPILE__)
    return __builtin_amdgcn_perm(__builtin_bit_cast(unsigned, a),
                                 __builtin_bit_cast(unsigned, b), 0x03020706u);
#else
    return 0u;
#endif
}

__device__ __forceinline__ float fast_exp2(float x) {
#if defined(__HIP_DEVICE_COMPILE__)
    return __builtin_amdgcn_exp2f(x);
#else
    return x;
#endif
}

__device__ __forceinline__ void async_copy16(const unsigned short* g, unsigned short* l) {
    __builtin_amdgcn_global_load_lds(
        (const __attribute__((address_space(1))) unsigned int*)g,
        (__attribute__((address_space(3))) unsigned int*)l, 16, 0, 0);
}

__device__ __forceinline__ f32x4 mfma16x16x16(short4v a, short4v b, f32x4 c) {
#if defined(__HIP_DEVICE_COMPILE__)
    return __builtin_amdgcn_mfma_f32_16x16x16bf16_1k(a, b, c, 0, 0, 0);
#else
    return c;
#endif
}

// ---------------- prep bodies ----------------
__device__ __forceinline__ void convert_body(
    const float* __restrict__ in, unsigned short* __restrict__ out, int blk)
{
    size_t i = ((size_t)blk * 256 + threadIdx.x) * 8;
    float4 v0 = *(const float4*)(in + i);
    float4 v1 = *(const float4*)(in + i + 4);
    ushort4 a, b;
    a.x = f2bf(v0.x); a.y = f2bf(v0.y); a.z = f2bf(v0.z); a.w = f2bf(v0.w);
    b.x = f2bf(v1.x); b.y = f2bf(v1.y); b.z = f2bf(v1.z); b.w = f2bf(v1.w);
    *(ushort4*)(out + i) = a;
    *(ushort4*)(out + i + 4) = b;
}

__device__ __forceinline__ void transpose_body(
    const float* __restrict__ in, unsigned short* __restrict__ out,
    int K, int N, int bx, int by, float T[64][65])
{
    const int tid = threadIdx.x;
    const int n0 = bx * 64, k0 = by * 64;
#pragma unroll
    for (int i = 0; i < 4; i++) {
        int idx = tid + i * 256;
        int r = idx >> 4, c4 = (idx & 15) * 4;
        float4 v = *(const float4*)(in + (size_t)(k0 + r) * N + n0 + c4);
        T[r][c4 + 0] = v.x; T[r][c4 + 1] = v.y; T[r][c4 + 2] = v.z; T[r][c4 + 3] = v.w;
    }
    __syncthreads();
#pragma unroll
    for (int i = 0; i < 4; i++) {
        int idx = tid + i * 256;
        int n = idx >> 4, k4 = (idx & 15) * 4;
        ushort4 o;
        o.x = f2bf(T[k4 + 0][n]); o.y = f2bf(T[k4 + 1][n]);
        o.z = f2bf(T[k4 + 2][n]); o.w = f2bf(T[k4 + 3][n]);
        *(ushort4*)(out + (size_t)(n0 + n) * K + k0 + k4) = o;
    }
}

__global__ __launch_bounds__(256) void prep(
    const float* __restrict__ x, const float* __restrict__ Wqkv, const float* __restrict__ Wo,
    unsigned short* __restrict__ xbf, unsigned short* __restrict__ wqkvT,
    unsigned short* __restrict__ woT)
{
    __shared__ float T[64][65];
    const int i = blockIdx.x;
    if (i < 2048) {
        convert_body(x, xbf, i);
    } else if (i < 2048 + 768) {
        int j = i - 2048;
        transpose_body(Wqkv, wqkvT, 1024, 3072, j % 48, j / 48, T);
    } else {
        int j = i - 2816;
        transpose_body(Wo, woT, 1024, 1024, j % 16, j / 16, T);
    }
}

__global__ __launch_bounds__(256) void convert_f32_bf16(
    const float* __restrict__ in, unsigned short* __restrict__ out)
{
    convert_body(in, out, blockIdx.x);
}

__global__ __launch_bounds__(256) void transpose_f32_bf16(
    const float* __restrict__ in, unsigned short* __restrict__ out, int K, int N)
{
    __shared__ float T[64][65];
    transpose_body(in, out, K, N, blockIdx.x, blockIdx.y, T);
}

// ---------------- GEMM1: qkv = Xbf @ WqkvT (+bqkv). Coalesced epilogue writes
// q/k row-major AND vt=[bh][d][s] directly (per-block v-columns are one aligned
// 64-col half with uniform h; transposed via the Tv LDS tile). ----------------
__global__ __launch_bounds__(256) void gemm_qkv_bf(
    const unsigned short* __restrict__ Xbf,  // [4096][1024] bf16
    const unsigned short* __restrict__ WT,   // [3072][1024] bf16
    const float* __restrict__ bias,
    unsigned short* __restrict__ qws, unsigned short* __restrict__ kws,
    unsigned short* __restrict__ vt)         // [32][64][2048]
{
    const int K = 1024;
    __shared__ __align__(16) unsigned short smem[128 * 136];  // staging union / C-tile
    __shared__ __align__(16) unsigned short Tv[64 * 146];     // v-transpose tile
    unsigned short* As = smem;
    unsigned short* Bs = smem + 8192;
    const int tid = threadIdx.x;
    const int m0 = blockIdx.y * 128, n0 = blockIdx.x * 128;
    const int phase = blockIdx.x % 3;   // 0: q|k, 1: v|q, 2: k|v
    const int wave = tid >> 6, lane = tid & 63;
    const int wm = (wave >> 1) * 64, wn = (wave & 1) * 64;
    const int quad = lane >> 4, l16 = lane & 15;
    const int lrow = lane >> 3, lgrp = lane & 7;
    const int sg = lgrp ^ lrow;

    f32x4 acc[4][4];
    const f32x4 Z4 = {0.f, 0.f, 0.f, 0.f};
#pragma unroll
    for (int i = 0; i < 4; i++)
#pragma unroll
        for (int j = 0; j < 4; j++) acc[i][j] = Z4;

    for (int k0 = 0; k0 < K; k0 += 64) {
        __syncthreads();
#pragma unroll
        for (int c = 0; c < 4; c++) {
            int nb = (wave * 4 + c) * 8;
            async_copy16(Xbf + (size_t)(m0 + nb + lrow) * K + k0 + sg * 8, &As[nb * 64]);
            async_copy16(WT  + (size_t)(n0 + nb + lrow) * K + k0 + sg * 8, &Bs[nb * 64]);
        }
        __syncthreads();
#pragma unroll
        for (int kk = 0; kk < 2; kk++) {
            int pg = ((kk * 4 + quad) ^ (l16 & 7)) * 8;
            bf16x8 af[4], bfr[4];
#pragma unroll
            for (int mi = 0; mi < 4; mi++) af[mi] = *(const bf16x8*)&As[(wm + mi * 16 + l16) * 64 + pg];
#pragma unroll
            for (int ni = 0; ni < 4; ni++) bfr[ni] = *(const bf16x8*)&Bs[(wn + ni * 16 + l16) * 64 + pg];
#pragma unroll
            for (int mi = 0; mi < 4; mi++)
#pragma unroll
                for (int ni = 0; ni < 4; ni++)
                    acc[mi][ni] = __builtin_amdgcn_mfma_f32_16x16x32_bf16(af[mi], bfr[ni], acc[mi][ni], 0, 0, 0);
        }
    }
    // ---- epilogue pass 1: bias (+k prescale) -> bf16 -> C-tile / Tv ----
    __syncthreads();
#pragma unroll
    for (int ni = 0; ni < 4; ni++) {
        int colL = wn + ni * 16 + l16;
        int col = n0 + colL;
        int rem = col % 192, t = rem >> 6;
        float bv = bias[col];
        if (t == 2) {  // wave-uniform per ni
#pragma unroll
            for (int mi = 0; mi < 4; mi++)
#pragma unroll
                for (int r = 0; r < 4; r++) {
                    int row = wm + mi * 16 + quad * 4 + r;
                    Tv[(colL & 63) * 146 + row] = f2bf(acc[mi][ni][r] + bv);
                }
        } else {
            float scl = (t == 1) ? 0.18033688f : 1.0f;  // 0.125*log2(e) folded into K
#pragma unroll
            for (int mi = 0; mi < 4; mi++)
#pragma unroll
                for (int r = 0; r < 4; r++) {
                    int row = wm + mi * 16 + quad * 4 + r;
                    smem[row * 136 + colL] = f2bf((acc[mi][ni][r] + bv) * scl);
                }
        }
    }
    __syncthreads();
    // ---- epilogue pass 2: coalesced 16B/lane stores ----
    if (phase == 0) {
#pragma unroll
        for (int i = 0; i < 8; i++) {
            int idx = tid + i * 256;
            int row = idx >> 4, g = idx & 15;
            int colL = g * 8;
            uint4 w = *(const uint4*)&smem[row * 136 + colL];
            int col = n0 + colL;
            int h = col / 192, rem = col % 192, t = rem >> 6, d = rem & 63;
            int grow = m0 + row;
            int b = grow >> 11, s = grow & 2047;
            unsigned short* dst = (t == 0) ? qws : kws;  // phase 0: never v
            *(uint4*)(dst + ((size_t)(b * 16 + h) * 2048 + s) * 64 + d) = w;
        }
    } else {
        const int qkb = (phase == 1) ? 64 : 0;   // local base of the q/k half
#pragma unroll
        for (int i = 0; i < 4; i++) {
            int idx = tid + i * 256;             // 128 rows x 8 groups
            int row = idx >> 3, g = idx & 7;
            int colL = qkb + g * 8;
            uint4 w = *(const uint4*)&smem[row * 136 + colL];
            int col = n0 + colL;
            int h = col / 192, rem = col % 192, t = rem >> 6, d = rem & 63;
            int grow = m0 + row;
            int b = grow >> 11, s = grow & 2047;
            unsigned short* dst = (t == 0) ? qws : kws;
            *(uint4*)(dst + ((size_t)(b * 16 + h) * 2048 + s) * 64 + d) = w;
        }
        const int vbase = (phase == 1) ? 0 : 64;
        const int hv = (n0 + vbase) / 192;       // uniform per block
        const int bb = m0 >> 11, s0 = m0 & 2047;
        unsigned short* vtb = vt + ((size_t)(bb * 16 + hv) * 64) * 2048 + s0;
#pragma unroll
        for (int i = 0; i < 4; i++) {
            int idx = tid + i * 256;             // 64 d x 16 row-groups
            int d = idx >> 4, rg = idx & 15;
            uint4 w = *(const uint4*)&Tv[d * 146 + rg * 8];
            *(uint4*)(vtb + (size_t)d * 2048 + rg * 8) = w;
        }
    }
}

// ---------------- Flash attention (causal), S-transposed, fine split-K ----------------
// Tiles 0..11 unsplit; 12..23 2-way; 24..31 3-way (all chunks <= 12 kv-iters).
// Chunk 0 of a split tile writes its UNNORMALIZED partial into ctx; chunks >= 1 into
// Opart. All split chunks record row-sums in lpart. Separate combine normalizes.
#define J(t, s, e, c) ((unsigned)(t) | ((unsigned)(s) << 8) | ((unsigned)(e) << 16) | ((unsigned)(c) << 24))
__device__ __constant__ unsigned ATTN_JOBS[60] = {
    J(22,0,12,0), J(23,0,12,0), J(23,12,24,1), J(11,0,12,0),
    J(20,0,11,0), J(21,0,11,0), J(21,11,22,1), J(22,12,23,1),
    J(30,0,11,0), J(31,0,11,0), J(31,11,22,1), J(10,0,11,0),
    J(18,0,10,0), J(19,0,10,0), J(19,10,20,1), J(20,11,21,1),
    J(27,0,10,0), J(28,0,10,0), J(28,10,20,1), J(29,0,10,0),
    J(29,10,20,1), J(29,20,30,2), J(30,11,21,1), J(30,21,31,2),
    J(31,22,32,2), J(9,0,10,0),
    J(16,0,9,0), J(17,0,9,0), J(17,9,18,1), J(18,10,19,1),
    J(24,0,9,0), J(25,0,9,0), J(25,9,18,1), J(26,0,9,0),
    J(26,9,18,1), J(26,18,27,2), J(27,10,19,1), J(27,19,28,2),
    J(28,20,29,2), J(8,0,9,0),
    J(14,0,8,0), J(15,0,8,0), J(15,8,16,1), J(16,9,17,1),
    J(24,9,17,1), J(24,17,25,2), J(25,18,26,2), J(7,0,8,0),
    J(12,0,7,0), J(13,0,7,0), J(13,7,14,1), J(14,8,15,1), J(6,0,7,0),
    J(12,7,13,1), J(5,0,6,0), J(4,0,5,0), J(3,0,4,0), J(2,0,3,0),
    J(1,0,2,0), J(0,0,1,0),
};
#undef J

__global__ __launch_bounds__(128) void attn(
    const unsigned short* __restrict__ qws, const unsigned short* __restrict__ kws,
    const unsigned short* __restrict__ vtws, unsigned short* __restrict__ ctx,
    unsigned short* __restrict__ Opart, float* __restrict__ lpart)
{
    __shared__ __align__(16) unsigned short Qs[64 * 64];
    __shared__ __align__(16) unsigned short Ks[64 * 64];
    __shared__ __align__(16) unsigned short Vt[64][72];

    const int tid = threadIdx.x;
    const int wave = tid >> 6, lane = tid & 63, quad = lane >> 4, l16 = lane & 15;
    const int lrow = lane >> 3, lgrp = lane & 7;
    const int sg = lgrp ^ lrow;

    const unsigned job = ATTN_JOBS[blockIdx.x >> 5];
    const int bh = blockIdx.x & 31;
    const int tile = job & 0xff;
    const int js = (job >> 8) & 0xff, je = (job >> 16) & 0xff;
    const int chunk = (job >> 24) & 0xff;
    const int q0 = tile * 64;
    const bool split = tile >= 12;

    const unsigned short* Q  = qws + (size_t)bh * 2048 * 64;
    const unsigned short* Kp = kws + (size_t)bh * 2048 * 64;
    const unsigned short* Vp = vtws + (size_t)bh * 64 * 2048;

#pragma unroll
    for (int c = 0; c < 4; c++) {
        int rb = (wave * 4 + c) * 8;
        async_copy16(Q + (size_t)(q0 + rb + lrow) * 64 + sg * 8, &Qs[rb * 64]);
    }

    const int wq = wave * 32;
    f32x4 o[4][2];
    const f32x4 Z4 = {0.f, 0.f, 0.f, 0.f};
#pragma unroll
    for (int dt = 0; dt < 4; dt++)
#pragma unroll
        for (int qt = 0; qt < 2; qt++) o[dt][qt] = Z4;
    float lsum[2] = {0.f, 0.f};

    for (int j = js; j < je; j++) {
        const int kb0 = j * 64;
        __syncthreads();
#pragma unroll
        for (int c = 0; c < 4; c++) {
            int rb = (wave * 4 + c) * 8;
            async_copy16(Kp + (size_t)(kb0 + rb + lrow) * 64 + sg * 8, &Ks[rb * 64]);
        }
#pragma unroll
        for (int ii = 0; ii < 4; ii++) {
            int id2 = tid + ii * 128;
            int row = id2 >> 3, c = (id2 & 7) * 8;
            *(uint4*)&Vt[row][c] = *(const uint4*)(Vp + (size_t)row * 2048 + kb0 + c);
        }
        __syncthreads();

        if (kb0 <= q0 + wq + 31) {
            f32x4 sc[4][2];
#pragma unroll
            for (int kt = 0; kt < 4; kt++)
#pragma unroll
                for (int qt = 0; qt < 2; qt++) sc[kt][qt] = Z4;
#pragma unroll
            for (int kk = 0; kk < 2; kk++) {
                int pg = ((kk * 4 + quad) ^ (l16 & 7)) * 8;
                bf16x8 ak[4], bq[2];
#pragma unroll
                for (int kt = 0; kt < 4; kt++) ak[kt] = *(const bf16x8*)&Ks[(kt * 16 + l16) * 64 + pg];
#pragma unroll
                for (int qt = 0; qt < 2; qt++) bq[qt] = *(const bf16x8*)&Qs[(wq + qt * 16 + l16) * 64 + pg];
#pragma unroll
                for (int kt = 0; kt < 4; kt++)
#pragma unroll
                    for (int qt = 0; qt < 2; qt++)
                        sc[kt][qt] = __builtin_amdgcn_mfma_f32_16x16x32_bf16(ak[kt], bq[qt], sc[kt][qt], 0, 0, 0);
            }
            short4v pb[4][2];
            if (kb0 + 63 <= q0 + wq) {
#pragma unroll
                for (int qt = 0; qt < 2; qt++)
#pragma unroll
                    for (int kt = 0; kt < 4; kt++) {
                        float p0 = fast_exp2(sc[kt][qt][0]);
                        float p1 = fast_exp2(sc[kt][qt][1]);
                        float p2 = fast_exp2(sc[kt][qt][2]);
                        float p3 = fast_exp2(sc[kt][qt][3]);
                        lsum[qt] += (p0 + p1) + (p2 + p3);
                        uint2 uu;
                        uu.x = pack_bf16x2_trunc(p0, p1);
                        uu.y = pack_bf16x2_trunc(p2, p3);
                        pb[kt][qt] = __builtin_bit_cast(short4v, uu);
                    }
            } else {
#pragma unroll
                for (int qt = 0; qt < 2; qt++) {
                    int qg = q0 + wq + qt * 16 + l16;
#pragma unroll
                    for (int kt = 0; kt < 4; kt++) {
                        float p[4];
#pragma unroll
                        for (int r = 0; r < 4; r++) {
                            int key = kb0 + kt * 16 + quad * 4 + r;
                            float t = fast_exp2(sc[kt][qt][r]);
                            p[r] = (key <= qg) ? t : 0.f;
                        }
                        lsum[qt] += (p[0] + p[1]) + (p[2] + p[3]);
                        uint2 uu;
                        uu.x = pack_bf16x2_trunc(p[0], p[1]);
                        uu.y = pack_bf16x2_trunc(p[2], p[3]);
                        pb[kt][qt] = __builtin_bit_cast(short4v, uu);
                    }
                }
            }
#pragma unroll
            for (int kt = 0; kt < 4; kt++) {
#pragma unroll
                for (int dt = 0; dt < 4; dt++) {
                    short4v av = *(const short4v*)&Vt[dt * 16 + l16][kt * 16 + quad * 4];
#pragma unroll
                    for (int qt = 0; qt < 2; qt++)
                        o[dt][qt] = mfma16x16x16(av, pb[kt][qt], o[dt][qt]);
                }
            }
        }
    }
#pragma unroll
    for (int qt = 0; qt < 2; qt++) {
        lsum[qt] += __shfl_xor(lsum[qt], 16);
        lsum[qt] += __shfl_xor(lsum[qt], 32);
    }
    const int b = bh >> 4, h = bh & 15;
    if (!split) {
#pragma unroll
        for (int qt = 0; qt < 2; qt++) {
            int qg = q0 + wq + qt * 16 + l16;
            float inv = 1.0f / lsum[qt];
#pragma unroll
            for (int dt = 0; dt < 4; dt++) {
                ushort4 ov;
                ov.x = f2bf(o[dt][qt][0] * inv);
                ov.y = f2bf(o[dt][qt][1] * inv);
                ov.z = f2bf(o[dt][qt][2] * inv);
                ov.w = f2bf(o[dt][qt][3] * inv);
                *(ushort4*)(ctx + (size_t)(b * 2048 + qg) * 1024 + h * 64 + dt * 16 + quad * 4) = ov;
            }
        }
    } else {
        const int ls = ((tile < 24) ? (tile - 12) * 2 + chunk
                                    : 24 + (tile - 24) * 3 + chunk);
        float* lp = lpart + ((size_t)bh * 48 + ls) * 64;
#pragma unroll
        for (int qt = 0; qt < 2; qt++) {
            int rl = wq + qt * 16 + l16;
            if (quad == 0) lp[rl] = lsum[qt];
        }
        if (chunk == 0) {
#pragma unroll
            for (int qt = 0; qt < 2; qt++) {
                int qg = q0 + wq + qt * 16 + l16;
#pragma unroll
                for (int dt = 0; dt < 4; dt++) {
                    ushort4 ov;
                    ov.x = f2bf(o[dt][qt][0]);
                    ov.y = f2bf(o[dt][qt][1]);
                    ov.z = f2bf(o[dt][qt][2]);
                    ov.w = f2bf(o[dt][qt][3]);
                    *(ushort4*)(ctx + (size_t)(b * 2048 + qg) * 1024 + h * 64 + dt * 16 + quad * 4) = ov;
                }
            }
        } else {
            const int os = (tile < 24) ? (tile - 12)
                                       : 12 + (tile - 24) * 2 + (chunk - 1);
            unsigned short* ob = Opart + ((size_t)bh * 28 + os) * 4096;
#pragma unroll
            for (int qt = 0; qt < 2; qt++) {
                int rl = wq + qt * 16 + l16;
#pragma unroll
                for (int dt = 0; dt < 4; dt++) {
                    ushort4 ov;
                    ov.x = f2bf(o[dt][qt][0]);
                    ov.y = f2bf(o[dt][qt][1]);
                    ov.z = f2bf(o[dt][qt][2]);
                    ov.w = f2bf(o[dt][qt][3]);
                    *(ushort4*)(ob + (size_t)rl * 64 + dt * 16 + quad * 4) = ov;
                }
            }
        }
    }
}

// ---------------- combine split-K partials: ctx = (ctx + sum Opart) / sum l ----------------
__global__ __launch_bounds__(256) void attn_combine(
    const unsigned short* __restrict__ Opart, const float* __restrict__ lpart,
    unsigned short* __restrict__ ctx)
{
    const int t = 12 + blockIdx.x;   // tiles 12..31
    const int bh = blockIdx.y;
    const int tid = threadIdx.x;
    const int row = tid >> 2, dg = (tid & 3) * 16;
    const int nch = (t < 24) ? 2 : 3;
    const int ls0 = (t < 24) ? (t - 12) * 2 : 24 + (t - 24) * 3;
    const float* lp = lpart + ((size_t)bh * 48 + ls0) * 64 + row;
    float lsum = lp[0] + lp[64];
    if (nch == 3) lsum += lp[128];
    const float inv = 1.0f / lsum;
    const int os0 = (t < 24) ? (t - 12) : 12 + (t - 24) * 2;
    const unsigned short* p1 = Opart + ((size_t)bh * 28 + os0) * 4096 + (size_t)row * 64 + dg;
    const int b = bh >> 4, h = bh & 15;
    unsigned short* dst = ctx + ((size_t)(b * 2048 + t * 64 + row)) * 1024 + h * 64 + dg;
#pragma unroll
    for (int g = 0; g < 2; g++) {
        ushort a0[8], a1[8], a2[8], ov[8];
        *(uint4*)a0 = *(const uint4*)(dst + g * 8);
        *(uint4*)a1 = *(const uint4*)(p1 + g * 8);
        if (nch == 3) *(uint4*)a2 = *(const uint4*)(p1 + 4096 + g * 8);
#pragma unroll
        for (int e = 0; e < 8; e++) {
            float f = bf2f(a0[e]) + bf2f(a1[e]);
            if (nch == 3) f += bf2f(a2[e]);
            ov[e] = f2bf(f * inv);
        }
        *(uint4*)(dst + g * 8) = *(const uint4*)ov;
    }
}

// ---------------- GEMM2: out = ctx @ Wo + bo (fp32 out), 64x128 tiles (512 blocks) ----------------
__global__ __launch_bounds__(256) void gemm_out(
    const unsigned short* __restrict__ Ctx, const unsigned short* __restrict__ WT,
    const float* __restrict__ bias, float* __restrict__ Out)
{
    const int K = 1024, N = 1024;
    __shared__ __align__(16) unsigned short As[64 * 64];
    __shared__ __align__(16) unsigned short Bs[128 * 64];
    const int tid = threadIdx.x;
    const int m0 = blockIdx.y * 64, n0 = blockIdx.x * 128;
    const int wave = tid >> 6, lane = tid & 63;
    const int wm = (wave >> 1) * 32, wn = (wave & 1) * 64;
    const int quad = lane >> 4, l16 = lane & 15;
    const int lrow = lane >> 3, lgrp = lane & 7;
    const int sg = lgrp ^ lrow;

    f32x4 acc[2][4];
    const f32x4 Z4 = {0.f, 0.f, 0.f, 0.f};
#pragma unroll
    for (int i = 0; i < 2; i++)
#pragma unroll
        for (int j = 0; j < 4; j++) acc[i][j] = Z4;

    for (int k0 = 0; k0 < K; k0 += 64) {
        __syncthreads();
#pragma unroll
        for (int c = 0; c < 2; c++) {
            int nb = (wave * 2 + c) * 8;
            async_copy16(Ctx + (size_t)(m0 + nb + lrow) * K + k0 + sg * 8, &As[nb * 64]);
        }
#pragma unroll
        for (int c = 0; c < 4; c++) {
            int nb = (wave * 4 + c) * 8;
            async_copy16(WT + (size_t)(n0 + nb + lrow) * K + k0 + sg * 8, &Bs[nb * 64]);
        }
        __syncthreads();
#pragma unroll
        for (int kk = 0; kk < 2; kk++) {
            int pg = ((kk * 4 + quad) ^ (l16 & 7)) * 8;
            bf16x8 af[2], bfr[4];
#pragma unroll
            for (int mi = 0; mi < 2; mi++) af[mi] = *(const bf16x8*)&As[(wm + mi * 16 + l16) * 64 + pg];
#pragma unroll
            for (int ni = 0; ni < 4; ni++) bfr[ni] = *(const bf16x8*)&Bs[(wn + ni * 16 + l16) * 64 + pg];
#pragma unroll
            for (int mi = 0; mi < 2; mi++)
#pragma unroll
                for (int ni = 0; ni < 4; ni++)
                    acc[mi][ni] = __builtin_amdgcn_mfma_f32_16x16x32_bf16(af[mi], bfr[ni], acc[mi][ni], 0, 0, 0);
        }
    }
#pragma unroll
    for (int mi = 0; mi < 2; mi++)
#pragma unroll
        for (int ni = 0; ni < 4; ni++) {
            int col = n0 + wn + ni * 16 + l16;
            float bv = bias[col];
#pragma unroll
            for (int r = 0; r < 4; r++) {
                int row = m0 + wm + mi * 16 + quad * 4 + r;
                Out[(size_t)row * N + col] = acc[mi][ni][r] + bv;
            }
        }
}

extern "C" void kernel_launch(void* const* d_in, const int* in_sizes, int n_in,
                              void* d_out, int out_size, void* d_ws, size_t ws_size,
                              hipStream_t stream) {
    const float* x    = (const float*)d_in[0];
    const float* Wqkv = (const float*)d_in[1];
    const float* bqkv = (const float*)d_in[2];
    const float* Wo   = (const float*)d_in[3];
    const float* bo   = (const float*)d_in[4];
    float* out = (float*)d_out;

    const size_t R = 4194304;  // ushorts per region (8 MB)
    unsigned short* q    = (unsigned short*)d_ws;
    unsigned short* k    = q + R;
    unsigned short* vt   = k + R;     // region 2: written directly by gemm_qkv
    unsigned short* ctx  = vt + R;    // region 3 (wqkvT before attn)
    unsigned short* xbf  = ctx + R;   // region 4: xbf during gemm; Opart/lpart during attn
    unsigned short* wqkvT = ctx;
    // split-K scratch in region 4 (xbf dead after gemm_qkv_bf):
    unsigned short* Opart = xbf;                           // 896 slots * 4096 ushorts
    float* lpart = (float*)(xbf + (size_t)896 * 4096);     // 1536 slots * 64 fp32

    if (ws_size >= 2 * (5 * R + 1048576)) {
        unsigned short* woT5 = q + 5 * R;
        prep<<<dim3(3072), 256, 0, stream>>>(x, Wqkv, Wo, xbf, wqkvT, woT5);
        gemm_qkv_bf<<<dim3(24, 32), 256, 0, stream>>>(xbf, wqkvT, bqkv, q, k, vt);
        attn<<<dim3(1920), 128, 0, stream>>>(q, k, vt, ctx, Opart, lpart);
        attn_combine<<<dim3(20, 32), 256, 0, stream>>>(Opart, lpart, ctx);
        gemm_out<<<dim3(8, 64), 256, 0, stream>>>(ctx, woT5, bo, out);
    } else {
        unsigned short* woT = q;  // alias: q dead after attn
        convert_f32_bf16<<<dim3(2048), 256, 0, stream>>>(x, xbf);
        transpose_f32_bf16<<<dim3(48, 16), 256, 0, stream>>>(Wqkv, wqkvT, 1024, 3072);
        gemm_qkv_bf<<<dim3(24, 32), 256, 0, stream>>>(xbf, wqkvT, bqkv, q, k, vt);
        attn<<<dim3(1920), 128, 0, stream>>>(q, k, vt, ctx, Opart, lpart);
        attn_combine<<<dim3(20, 32), 256, 0, stream>>>(Opart, lpart, ctx);
        transpose_f32_bf16<<<dim3(16, 16), 256, 0, stream>>>(Wo, woT, 1024, 1024);
        gemm_out<<<dim3(8, 64), 256, 0, stream>>>(ctx, woT, bo, out);
    }
}